// Round 9
// baseline (398865.430 us; speedup 1.0000x reference)
//
#include <hip/hip_runtime.h>

#define IDIM  64
#define HDIM  512
#define T_LEN 65536
#define NWG   128
#define NTHR  512
#define NSLOT (2 * HDIM)   // 0..511 = h1, 512..1023 = h2

// Private per-WG mailboxes: tagged 8B records {hi32=tick tag, lo32=float bits},
// double-buffered by tag parity. Producers PUSH to all mailboxes; each WG polls
// only its own. Same tag protocol as the verified R5 kernel.
__device__ unsigned long long g_mb[2][NWG][NSLOT];

__device__ __forceinline__ unsigned long long pack(float v, int k) {
  return ((unsigned long long)(unsigned)k << 32) | (unsigned long long)__float_as_uint(v);
}

__global__ void lstm_init() {
  const int t = threadIdx.x;
  for (int w = 0; w < NWG; ++w)
    for (int e = t; e < HDIM; e += blockDim.x) {
      g_mb[1][w][e]        = 0xFFFFFFFF00000000ull; // h1 tag=-1 val=0 : read at tick 0
      g_mb[0][w][e]        = 0xFFFFFFFE00000000ull; // h1 never-match : overwritten at tick 0
      g_mb[0][w][HDIM + e] = 0xFFFFFFFF00000000ull; // h2 tag=-1 val=0 : read at tick 0
      g_mb[1][w][HDIM + e] = 0x0000000000000000ull; // h2 tag=0  val=0 : h2(-1), read at tick 1
    }
}

__global__ __launch_bounds__(NTHR)
__attribute__((amdgpu_waves_per_eu(2, 2)))   // R5 shape: VGPR=88, weights resident
void lstm_main(
    const float* __restrict__ x_seq,
    const float* __restrict__ W_ih1, const float* __restrict__ W_hh1,
    const float* __restrict__ b_ih1, const float* __restrict__ b_hh1,
    const float* __restrict__ W_ih2, const float* __restrict__ W_hh2,
    const float* __restrict__ b_ih2, const float* __restrict__ b_hh2,
    const float* __restrict__ W_out, const float* __restrict__ b_out,
    float* __restrict__ out)
{
  const int wg   = blockIdx.x;
  const int tid  = threadIdx.x;
  const int wave = tid >> 6;      // 0..7
  const int role = wave >> 2;     // 0 = layer1, 1 = layer2
  const int lane = tid & 63;
  const int g    = lane >> 4;     // gate 0..3 (i,f,g,o)
  const int s    = lane & 15;     // strip 0..15
  const int j    = wg * 4 + (wave & 3);   // owned hidden index for this (j,layer) wave
  const int r    = g * HDIM + j;          // gate row in [0,2048)

  // ---- weights -> VGPRs: ONE array, role-dependent contents (max 64 live floats) ----
  float w[64];
  if (role == 0) {
#pragma unroll
    for (int m = 0; m < 36; ++m) {
      int e = s * 36 + m;
      w[m] = (e < HDIM) ? W_hh1[(size_t)r * HDIM + e]
                        : W_ih1[(size_t)r * IDIM + (e - HDIM)];
    }
#pragma unroll
    for (int m = 0; m < 36; ++m) asm volatile("" : "+v"(w[m]));  // forbid remat
  } else {
#pragma unroll
    for (int c = 0; c < 16; ++c) {
#pragma unroll
      for (int i = 0; i < 4; ++i) {
        int er = s * 64 + ((c + s) & 15) * 4 + i;   // 0..1023
        w[c * 4 + i] = (er < HDIM) ? W_ih2[(size_t)r * HDIM + er]
                                   : W_hh2[(size_t)r * HDIM + (er - HDIM)];
      }
    }
#pragma unroll
    for (int m = 0; m < 64; ++m) asm volatile("" : "+v"(w[m]));  // forbid remat
  }
  const float bsel = (role == 0) ? (b_ih1[r] + b_hh1[r]) : (b_ih2[r] + b_hh2[r]);

  float cst = 0.f;                 // cell state for owned (j, layer)
  int bud = 1 << 24;               // GLOBAL spin budget: fail fast, not per-tick

  __shared__ __align__(16) float vec[2][HDIM + IDIM + HDIM]; // [h1 | x | h2] x2

  for (int k = 0; k <= T_LEN; ++k) {
    const unsigned expect = (unsigned)(k - 1);
    const int p1  = (k + 1) & 1;  // h1 tag k-1 parity
    const int p2  = k & 1;        // h2 tag k-1 parity
    const int buf = k & 1;

    // x load issued before the poll so its latency hides under it
    float xv = 0.f;
    if (tid < IDIM && k < T_LEN) xv = x_seq[(size_t)k * IDIM + tid];

    // ---- poll OWN mailbox only: thread tid watches h1 slot tid + h2 slot 512+tid ----
    unsigned long long* s1 = &g_mb[p1][wg][tid];
    unsigned long long* s2 = &g_mb[p2][wg][HDIM + tid];
    unsigned long long a = 0, b = 0;
    bool ok1 = false, ok2 = false;
    do {
      if (!ok1) {
        a = __hip_atomic_load(s1, __ATOMIC_RELAXED, __HIP_MEMORY_SCOPE_AGENT);
        ok1 = ((unsigned)(a >> 32) == expect);
      }
      if (!ok2) {
        b = __hip_atomic_load(s2, __ATOMIC_RELAXED, __HIP_MEMORY_SCOPE_AGENT);
        ok2 = ((unsigned)(b >> 32) == expect);
      }
    } while ((!ok1 || !ok2) && --bud > 0);

    vec[buf][tid] = __uint_as_float((unsigned)a);
    vec[buf][HDIM + IDIM + tid] = __uint_as_float((unsigned)b);
    if (tid < IDIM) vec[buf][HDIM + tid] = xv;
    __syncthreads();   // only barrier per tick; vec is double-buffered

    // ---- compute: role 0 = layer1 step k; role 1 = layer2 step k-1 ----
    const bool active = (role == 0) ? (k < T_LEN) : (k > 0);
    if (active) {
      float acc = 0.f;
      if (role == 0) {
#pragma unroll
        for (int mc = 0; mc < 9; ++mc) {
          const float4 hv = *reinterpret_cast<const float4*>(&vec[buf][s * 36 + mc * 4]);
          acc = fmaf(w[mc * 4 + 0], hv.x, acc);
          acc = fmaf(w[mc * 4 + 1], hv.y, acc);
          acc = fmaf(w[mc * 4 + 2], hv.z, acc);
          acc = fmaf(w[mc * 4 + 3], hv.w, acc);
        }
      } else {
        const int vb = (s < 8) ? 0 : IDIM;  // skip the x-gap for the h2 half
#pragma unroll
        for (int c = 0; c < 16; ++c) {
          const int off = s * 64 + ((c + s) & 15) * 4 + vb;
          const float4 hv = *reinterpret_cast<const float4*>(&vec[buf][off]);
          acc = fmaf(w[c * 4 + 0], hv.x, acc);
          acc = fmaf(w[c * 4 + 1], hv.y, acc);
          acc = fmaf(w[c * 4 + 2], hv.z, acc);
          acc = fmaf(w[c * 4 + 3], hv.w, acc);
        }
      }
      acc += __shfl_xor(acc, 8, 16);
      acc += __shfl_xor(acc, 4, 16);
      acc += __shfl_xor(acc, 2, 16);
      acc += __shfl_xor(acc, 1, 16);

      // per-group activation (tanh via 2*sigmoid(2x)-1), then broadcast activated gates
      const float xs  = acc + bsel;
      const float xin = (g == 2) ? 2.f * xs : xs;
      const float sgm = 1.f / (1.f + expf(-xin));
      const float act = (g == 2) ? 2.f * sgm - 1.f : sgm;
      const float ai = __shfl(act, 0, 64);
      const float af = __shfl(act, 16, 64);
      const float ag = __shfl(act, 32, 64);
      const float ao = __shfl(act, 48, 64);
      cst = af * cst + ai * ag;
      const float tc = 2.f / (1.f + expf(-2.f * cst)) - 1.f;   // tanh(cst)
      const float hv = ao * tc;

      // ---- PUSH publish: every lane stores to 2 consumer mailboxes (128 total) ----
      const int vidx = (role == 0) ? j : (HDIM + j);
      const int par  = (role == 0) ? (k & 1) : ((k + 1) & 1);
      const unsigned long long rec = pack(hv, k);
      __hip_atomic_store(&g_mb[par][lane][vidx], rec,
                         __ATOMIC_RELAXED, __HIP_MEMORY_SCOPE_AGENT);
      __hip_atomic_store(&g_mb[par][lane + 64][vidx], rec,
                         __ATOMIC_RELAXED, __HIP_MEMORY_SCOPE_AGENT);
    }
    // no trailing barrier: double-buffered vec + per-tick barrier keep WAR safe
  }

  // ---- final output: out = W_out . h2(T-1) + b_out  (h2 tag T_LEN, parity 1) ----
  if (wg == 0 && wave == 0) {
    float acc = 0.f;
    int bud2 = 1 << 24;
#pragma unroll
    for (int e = 0; e < HDIM / 64; ++e) {
      const int idx = lane + e * 64;
      unsigned long long u;
      do {
        u = __hip_atomic_load(&g_mb[1][0][HDIM + idx], __ATOMIC_RELAXED, __HIP_MEMORY_SCOPE_AGENT);
      } while ((unsigned)(u >> 32) != (unsigned)T_LEN && --bud2 > 0);
      acc = fmaf(W_out[idx], __uint_as_float((unsigned)u), acc);
    }
    acc += __shfl_xor(acc, 32, 64);
    acc += __shfl_xor(acc, 16, 64);
    acc += __shfl_xor(acc, 8, 64);
    acc += __shfl_xor(acc, 4, 64);
    acc += __shfl_xor(acc, 2, 64);
    acc += __shfl_xor(acc, 1, 64);
    if (lane == 0) out[0] = acc + b_out[0];
  }
}

extern "C" void kernel_launch(void* const* d_in, const int* in_sizes, int n_in,
                              void* d_out, int out_size, void* d_ws, size_t ws_size,
                              hipStream_t stream) {
  const float* x_seq = (const float*)d_in[0];
  const float* W_ih1 = (const float*)d_in[1];
  const float* W_hh1 = (const float*)d_in[2];
  const float* b_ih1 = (const float*)d_in[3];
  const float* b_hh1 = (const float*)d_in[4];
  const float* W_ih2 = (const float*)d_in[5];
  const float* W_hh2 = (const float*)d_in[6];
  const float* b_ih2 = (const float*)d_in[7];
  const float* b_hh2 = (const float*)d_in[8];
  const float* W_out = (const float*)d_in[9];
  const float* b_out = (const float*)d_in[10];
  float* out = (float*)d_out;

  hipLaunchKernelGGL(lstm_init, dim3(1), dim3(256), 0, stream);
  hipLaunchKernelGGL(lstm_main, dim3(NWG), dim3(NTHR), 0, stream,
                     x_seq, W_ih1, W_hh1, b_ih1, b_hh1,
                     W_ih2, W_hh2, b_ih2, b_hh2, W_out, b_out, out);
}

// Round 10
// 151215.210 us; speedup vs baseline: 2.6377x; 2.6377x over previous
//
#include <hip/hip_runtime.h>

#define IDIM  64
#define HDIM  512
#define T_LEN 65536
#define NWG   64
#define NTHR  512

// Tagged hidden state: high 32 bits = tick tag, low 32 bits = float payload.
// The tag check doubles as the device-wide barrier (data+signal in one 8B word).
// Protocol identical to the verified R5 kernel; only ownership/WG-count changed.
__device__ unsigned long long g_h1[2][HDIM];
__device__ unsigned long long g_h2[2][HDIM];

__device__ __forceinline__ unsigned long long pack(float v, int k) {
  return ((unsigned long long)(unsigned)k << 32) | (unsigned long long)__float_as_uint(v);
}

__global__ void lstm_init() {
  int t = threadIdx.x;
  for (int e = t; e < HDIM; e += blockDim.x) {
    g_h1[0][e] = 0xFFFFFFFF00000000ull;  // tag=-1, val=0
    g_h1[1][e] = 0xFFFFFFFF00000000ull;  // read at tick 0 (expect -1)
    g_h2[0][e] = 0xFFFFFFFF00000000ull;  // read at tick 0 (expect -1)
    g_h2[1][e] = 0x0000000000000000ull;  // tag=0,val=0: h2(-1), read at tick 1
  }
}

__global__ __launch_bounds__(NTHR)
__attribute__((amdgpu_waves_per_eu(2, 2)))   // 256-VGPR budget: keep 128 weight floats resident
void lstm_main(
    const float* __restrict__ x_seq,
    const float* __restrict__ W_ih1, const float* __restrict__ W_hh1,
    const float* __restrict__ b_ih1, const float* __restrict__ b_hh1,
    const float* __restrict__ W_ih2, const float* __restrict__ W_hh2,
    const float* __restrict__ b_ih2, const float* __restrict__ b_hh2,
    const float* __restrict__ W_out, const float* __restrict__ b_out,
    float* __restrict__ out)
{
  const int wg   = blockIdx.x;
  const int tid  = threadIdx.x;
  const int wave = tid >> 6;      // 0..7
  const int role = wave >> 2;     // 0 = layer1 (waves 0-3), 1 = layer2 (waves 4-7)
  const int lane = tid & 63;
  const int g    = lane >> 4;     // gate 0..3 (i,f,g,o)
  const int s    = lane & 15;     // strip 0..15
  const int j0   = wg * 8 + (wave & 3) * 2;   // first owned hidden index
  const int j1   = j0 + 1;                    // second owned hidden index
  const int rA   = g * HDIM + j0;             // gate rows in [0,2048)
  const int rB   = g * HDIM + j1;

  // ---- weights -> VGPRs: TWO jobs per wave, shared column strips ----
  float wA[64], wB[64];
  if (role == 0) {
    // layer1 row = [W_hh1[r,0:512] | W_ih1[r,0:64]]; lane covers e = s*36 .. s*36+35
#pragma unroll
    for (int m = 0; m < 36; ++m) {
      int e = s * 36 + m;
      wA[m] = (e < HDIM) ? W_hh1[(size_t)rA * HDIM + e] : W_ih1[(size_t)rA * IDIM + (e - HDIM)];
      wB[m] = (e < HDIM) ? W_hh1[(size_t)rB * HDIM + e] : W_ih1[(size_t)rB * IDIM + (e - HDIM)];
    }
#pragma unroll
    for (int m = 0; m < 36; ++m) { asm volatile("" : "+v"(wA[m])); asm volatile("" : "+v"(wB[m])); }
  } else {
    // layer2 row = [W_ih2[r,0:512] | W_hh2[r,0:512]]; lane covers e = s*64 .. s*64+63,
    // chunk-rotated by s to avoid LDS bank conflicts on the stride-256B read pattern.
#pragma unroll
    for (int c = 0; c < 16; ++c) {
#pragma unroll
      for (int i = 0; i < 4; ++i) {
        int er = s * 64 + ((c + s) & 15) * 4 + i;   // 0..1023
        wA[c*4+i] = (er < HDIM) ? W_ih2[(size_t)rA * HDIM + er] : W_hh2[(size_t)rA * HDIM + (er - HDIM)];
        wB[c*4+i] = (er < HDIM) ? W_ih2[(size_t)rB * HDIM + er] : W_hh2[(size_t)rB * HDIM + (er - HDIM)];
      }
    }
#pragma unroll
    for (int m = 0; m < 64; ++m) { asm volatile("" : "+v"(wA[m])); asm volatile("" : "+v"(wB[m])); }
  }
  const float bselA = (role == 0) ? (b_ih1[rA] + b_hh1[rA]) : (b_ih2[rA] + b_hh2[rA]);
  const float bselB = (role == 0) ? (b_ih1[rB] + b_hh1[rB]) : (b_ih2[rB] + b_hh2[rB]);

  float cstA = 0.f, cstB = 0.f;    // cell states for owned (j0,j1)
  int bud = 1 << 24;               // GLOBAL spin budget: fail fast, not per-tick

  __shared__ __align__(16) float vec[2][HDIM + IDIM + HDIM]; // [h1 | x | h2] x2

  for (int k = 0; k <= T_LEN; ++k) {
    const unsigned expect = (unsigned)(k - 1);
    const int p1  = (k + 1) & 1;  // h1 tag k-1 parity
    const int p2  = k & 1;        // h2 tag k-1 parity
    const int buf = k & 1;

    // x load issued before the poll so its latency hides under it
    float xv = 0.f;
    if (tid < IDIM && k < T_LEN) xv = x_seq[(size_t)k * IDIM + tid];

    // ---- per-thread spin on this thread's two slots (verified R5 protocol) ----
    unsigned long long a = 0, b = 0;
    bool ok1 = false, ok2 = false;
    do {
      if (!ok1) {
        a = __hip_atomic_load(&g_h1[p1][tid], __ATOMIC_RELAXED, __HIP_MEMORY_SCOPE_AGENT);
        ok1 = ((unsigned)(a >> 32) == expect);
      }
      if (!ok2) {
        b = __hip_atomic_load(&g_h2[p2][tid], __ATOMIC_RELAXED, __HIP_MEMORY_SCOPE_AGENT);
        ok2 = ((unsigned)(b >> 32) == expect);
      }
    } while ((!ok1 || !ok2) && --bud > 0);

    vec[buf][tid] = __uint_as_float((unsigned)a);
    vec[buf][HDIM + IDIM + tid] = __uint_as_float((unsigned)b);
    if (tid < IDIM) vec[buf][HDIM + tid] = xv;
    __syncthreads();   // only barrier per tick; vec is double-buffered

    // ---- compute: role 0 = layer1 step k; role 1 = layer2 step k-1 ----
    const bool active = (role == 0) ? (k < T_LEN) : (k > 0);
    if (active) {
      float accA = 0.f, accB = 0.f;
      if (role == 0) {
#pragma unroll
        for (int mc = 0; mc < 9; ++mc) {
          const float4 hv = *reinterpret_cast<const float4*>(&vec[buf][s * 36 + mc * 4]);
          accA = fmaf(wA[mc*4+0], hv.x, accA); accB = fmaf(wB[mc*4+0], hv.x, accB);
          accA = fmaf(wA[mc*4+1], hv.y, accA); accB = fmaf(wB[mc*4+1], hv.y, accB);
          accA = fmaf(wA[mc*4+2], hv.z, accA); accB = fmaf(wB[mc*4+2], hv.z, accB);
          accA = fmaf(wA[mc*4+3], hv.w, accA); accB = fmaf(wB[mc*4+3], hv.w, accB);
        }
      } else {
        const int vb = (s < 8) ? 0 : IDIM;  // skip the x-gap for the h2 half
#pragma unroll
        for (int c = 0; c < 16; ++c) {
          const int off = s * 64 + ((c + s) & 15) * 4 + vb;
          const float4 hv = *reinterpret_cast<const float4*>(&vec[buf][off]);
          accA = fmaf(wA[c*4+0], hv.x, accA); accB = fmaf(wB[c*4+0], hv.x, accB);
          accA = fmaf(wA[c*4+1], hv.y, accA); accB = fmaf(wB[c*4+1], hv.y, accB);
          accA = fmaf(wA[c*4+2], hv.z, accA); accB = fmaf(wB[c*4+2], hv.z, accB);
          accA = fmaf(wA[c*4+3], hv.w, accA); accB = fmaf(wB[c*4+3], hv.w, accB);
        }
      }
      accA += __shfl_xor(accA, 8, 16);  accB += __shfl_xor(accB, 8, 16);
      accA += __shfl_xor(accA, 4, 16);  accB += __shfl_xor(accB, 4, 16);
      accA += __shfl_xor(accA, 2, 16);  accB += __shfl_xor(accB, 2, 16);
      accA += __shfl_xor(accA, 1, 16);  accB += __shfl_xor(accB, 1, 16);

      // per-group activation (tanh via 2*sigmoid(2x)-1), then broadcast activated gates
      const float xsA  = accA + bselA;
      const float xsB  = accB + bselB;
      const float xinA = (g == 2) ? 2.f * xsA : xsA;
      const float xinB = (g == 2) ? 2.f * xsB : xsB;
      const float sgmA = 1.f / (1.f + expf(-xinA));
      const float sgmB = 1.f / (1.f + expf(-xinB));
      const float actA = (g == 2) ? 2.f * sgmA - 1.f : sgmA;
      const float actB = (g == 2) ? 2.f * sgmB - 1.f : sgmB;
      const float aiA = __shfl(actA, 0, 64),  aiB = __shfl(actB, 0, 64);
      const float afA = __shfl(actA, 16, 64), afB = __shfl(actB, 16, 64);
      const float agA = __shfl(actA, 32, 64), agB = __shfl(actB, 32, 64);
      const float aoA = __shfl(actA, 48, 64), aoB = __shfl(actB, 48, 64);
      cstA = afA * cstA + aiA * agA;
      cstB = afB * cstB + aiB * agB;
      const float tcA = 2.f / (1.f + expf(-2.f * cstA)) - 1.f;   // tanh(cstA)
      const float tcB = 2.f / (1.f + expf(-2.f * cstB)) - 1.f;
      const float hvA = aoA * tcA;
      const float hvB = aoB * tcB;
      if (lane == 0) {
        if (role == 0) {
          __hip_atomic_store(&g_h1[k & 1][j0], pack(hvA, k), __ATOMIC_RELAXED, __HIP_MEMORY_SCOPE_AGENT);
          __hip_atomic_store(&g_h1[k & 1][j1], pack(hvB, k), __ATOMIC_RELAXED, __HIP_MEMORY_SCOPE_AGENT);
        } else {
          __hip_atomic_store(&g_h2[(k + 1) & 1][j0], pack(hvA, k), __ATOMIC_RELAXED, __HIP_MEMORY_SCOPE_AGENT);
          __hip_atomic_store(&g_h2[(k + 1) & 1][j1], pack(hvB, k), __ATOMIC_RELAXED, __HIP_MEMORY_SCOPE_AGENT);
        }
      }
    }
    // no trailing barrier: double-buffered vec + per-tick barrier keep WAR safe
  }

  // ---- final output: out = W_out . h2(T-1) + b_out  (tag T_LEN, parity 1) ----
  if (wg == 0 && wave == 0) {
    float acc = 0.f;
    int bud2 = 1 << 24;
#pragma unroll
    for (int e = 0; e < HDIM / 64; ++e) {
      const int idx = lane + e * 64;
      unsigned long long u;
      do {
        u = __hip_atomic_load(&g_h2[1][idx], __ATOMIC_RELAXED, __HIP_MEMORY_SCOPE_AGENT);
      } while ((unsigned)(u >> 32) != (unsigned)T_LEN && --bud2 > 0);
      acc = fmaf(W_out[idx], __uint_as_float((unsigned)u), acc);
    }
    acc += __shfl_xor(acc, 32, 64);
    acc += __shfl_xor(acc, 16, 64);
    acc += __shfl_xor(acc, 8, 64);
    acc += __shfl_xor(acc, 4, 64);
    acc += __shfl_xor(acc, 2, 64);
    acc += __shfl_xor(acc, 1, 64);
    if (lane == 0) out[0] = acc + b_out[0];
  }
}

extern "C" void kernel_launch(void* const* d_in, const int* in_sizes, int n_in,
                              void* d_out, int out_size, void* d_ws, size_t ws_size,
                              hipStream_t stream) {
  const float* x_seq = (const float*)d_in[0];
  const float* W_ih1 = (const float*)d_in[1];
  const float* W_hh1 = (const float*)d_in[2];
  const float* b_ih1 = (const float*)d_in[3];
  const float* b_hh1 = (const float*)d_in[4];
  const float* W_ih2 = (const float*)d_in[5];
  const float* W_hh2 = (const float*)d_in[6];
  const float* b_ih2 = (const float*)d_in[7];
  const float* b_hh2 = (const float*)d_in[8];
  const float* W_out = (const float*)d_in[9];
  const float* b_out = (const float*)d_in[10];
  float* out = (float*)d_out;

  hipLaunchKernelGGL(lstm_init, dim3(1), dim3(256), 0, stream);
  hipLaunchKernelGGL(lstm_main, dim3(NWG), dim3(NTHR), 0, stream,
                     x_seq, W_ih1, W_hh1, b_ih1, b_hh1,
                     W_ih2, W_hh2, b_ih2, b_hh2, W_out, b_out, out);
}